// Round 1
// baseline (3018.356 us; speedup 1.0000x reference)
//
#include <hip/hip_runtime.h>

#define DD 64
#define NT 256

__device__ __forceinline__ float silu_f(float x) {
    return x / (1.0f + __expf(-x));
}

// ---------------------------------------------------------------------------
// Edge kernel: one thread per edge.
//   e_in = [h[row](64), h[col](64), radial(1), edge_attr(2)]  (131)
//   e1 = silu(e_in @ We1 + be1); ef = silu(e1 @ We2 + be2)
//   scale = silu(ef @ Wc1 + bc1) @ Wc2
//   atomic scatter: agg_h[row] += ef ; agg_c[row] += clamp(diff*scale) ; cnt[row]++
// Intermediates staged in per-thread LDS columns (lds[k*NT+tid]) so k-loops
// stay rolled without scratch spills. No __syncthreads needed (column-private).
// ---------------------------------------------------------------------------
__global__ __launch_bounds__(NT) void egcl_edge_kernel(
    const float* __restrict__ h,
    const float* __restrict__ coord,
    const int*   __restrict__ ei,
    const float* __restrict__ ea,
    const float* __restrict__ We1, const float* __restrict__ be1,
    const float* __restrict__ We2, const float* __restrict__ be2,
    const float* __restrict__ Wc1, const float* __restrict__ bc1,
    const float* __restrict__ Wc2,
    float* __restrict__ agg_h,   // [N,64]  (aliases d_out h region)
    float* __restrict__ agg_c,   // [N,3]   (aliases d_out coord region)
    float* __restrict__ cnt,     // [N]     (in d_ws)
    int E)
{
    __shared__ float lds[DD * NT];
    const int tid = threadIdx.x;
    const int e = blockIdx.x * NT + tid;
    if (e >= E) return;

    const int row = ei[e];
    const int col = ei[E + e];

    const float dx = coord[row*3+0] - coord[col*3+0];
    const float dy = coord[row*3+1] - coord[col*3+1];
    const float dz = coord[row*3+2] - coord[col*3+2];
    const float radial = dx*dx + dy*dy + dz*dz;

    // ---- layer 1: 131 -> 64 ----
    float acc[DD];
    #pragma unroll
    for (int d = 0; d < DD; ++d) acc[d] = be1[d];

    const float* hr = h + (size_t)row * DD;
    for (int k0 = 0; k0 < DD; k0 += 4) {
        const float4 v = *reinterpret_cast<const float4*>(hr + k0);
        const float* w0 = We1 + (size_t)(k0 + 0) * DD;
        const float* w1 = We1 + (size_t)(k0 + 1) * DD;
        const float* w2 = We1 + (size_t)(k0 + 2) * DD;
        const float* w3 = We1 + (size_t)(k0 + 3) * DD;
        #pragma unroll
        for (int d = 0; d < DD; ++d) acc[d] = fmaf(v.x, w0[d], acc[d]);
        #pragma unroll
        for (int d = 0; d < DD; ++d) acc[d] = fmaf(v.y, w1[d], acc[d]);
        #pragma unroll
        for (int d = 0; d < DD; ++d) acc[d] = fmaf(v.z, w2[d], acc[d]);
        #pragma unroll
        for (int d = 0; d < DD; ++d) acc[d] = fmaf(v.w, w3[d], acc[d]);
    }
    const float* hc = h + (size_t)col * DD;
    for (int k0 = 0; k0 < DD; k0 += 4) {
        const float4 v = *reinterpret_cast<const float4*>(hc + k0);
        const float* w0 = We1 + (size_t)(DD + k0 + 0) * DD;
        const float* w1 = We1 + (size_t)(DD + k0 + 1) * DD;
        const float* w2 = We1 + (size_t)(DD + k0 + 2) * DD;
        const float* w3 = We1 + (size_t)(DD + k0 + 3) * DD;
        #pragma unroll
        for (int d = 0; d < DD; ++d) acc[d] = fmaf(v.x, w0[d], acc[d]);
        #pragma unroll
        for (int d = 0; d < DD; ++d) acc[d] = fmaf(v.y, w1[d], acc[d]);
        #pragma unroll
        for (int d = 0; d < DD; ++d) acc[d] = fmaf(v.z, w2[d], acc[d]);
        #pragma unroll
        for (int d = 0; d < DD; ++d) acc[d] = fmaf(v.w, w3[d], acc[d]);
    }
    {
        const float a0 = ea[(size_t)e * 2 + 0];
        const float a1 = ea[(size_t)e * 2 + 1];
        const float* wr  = We1 + (size_t)128 * DD;
        const float* wa0 = We1 + (size_t)129 * DD;
        const float* wa1 = We1 + (size_t)130 * DD;
        #pragma unroll
        for (int d = 0; d < DD; ++d) acc[d] = fmaf(radial, wr[d], acc[d]);
        #pragma unroll
        for (int d = 0; d < DD; ++d) acc[d] = fmaf(a0, wa0[d], acc[d]);
        #pragma unroll
        for (int d = 0; d < DD; ++d) acc[d] = fmaf(a1, wa1[d], acc[d]);
    }
    #pragma unroll
    for (int d = 0; d < DD; ++d) lds[d * NT + tid] = silu_f(acc[d]);

    // ---- layer 2: 64 -> 64 ----
    float acc2[DD];
    #pragma unroll
    for (int d = 0; d < DD; ++d) acc2[d] = be2[d];
    for (int k = 0; k < DD; ++k) {
        const float a = lds[k * NT + tid];
        const float* w = We2 + (size_t)k * DD;
        #pragma unroll
        for (int d = 0; d < DD; ++d) acc2[d] = fmaf(a, w[d], acc2[d]);
    }
    #pragma unroll
    for (int d = 0; d < DD; ++d) lds[d * NT + tid] = silu_f(acc2[d]); // edge_feat

    // ---- coord head: 64 -> 64 -> 1 ----
    float acc3[DD];
    #pragma unroll
    for (int d = 0; d < DD; ++d) acc3[d] = bc1[d];
    for (int k = 0; k < DD; ++k) {
        const float a = lds[k * NT + tid];
        const float* w = Wc1 + (size_t)k * DD;
        #pragma unroll
        for (int d = 0; d < DD; ++d) acc3[d] = fmaf(a, w[d], acc3[d]);
    }
    float scale = 0.0f;
    #pragma unroll
    for (int d = 0; d < DD; ++d) scale = fmaf(silu_f(acc3[d]), Wc2[d], scale);

    float tx = dx * scale, ty = dy * scale, tz = dz * scale;
    tx = fminf(fmaxf(tx, -100.0f), 100.0f);
    ty = fminf(fmaxf(ty, -100.0f), 100.0f);
    tz = fminf(fmaxf(tz, -100.0f), 100.0f);

    atomicAdd(&agg_c[(size_t)row * 3 + 0], tx);
    atomicAdd(&agg_c[(size_t)row * 3 + 1], ty);
    atomicAdd(&agg_c[(size_t)row * 3 + 2], tz);
    atomicAdd(&cnt[row], 1.0f);

    float* ah = agg_h + (size_t)row * DD;
    for (int d = 0; d < DD; ++d) {
        atomicAdd(&ah[d], lds[d * NT + tid]);
    }
}

// ---------------------------------------------------------------------------
// Node kernel: one thread per node. Reads agg_h/agg_c in-place from d_out,
// finalizes h_out and coord_out in-place (each thread owns its slots).
// ---------------------------------------------------------------------------
__global__ __launch_bounds__(NT) void egcl_node_kernel(
    const float* __restrict__ h,
    const float* __restrict__ coord,
    const float* __restrict__ Wn1, const float* __restrict__ bn1,
    const float* __restrict__ Wn2, const float* __restrict__ bn2,
    float* __restrict__ out_h,   // in: agg_h, out: h_out
    float* __restrict__ out_c,   // in: agg_c, out: coord_out
    const float* __restrict__ cnt,
    int N)
{
    __shared__ float lds[DD * NT];
    const int tid = threadIdx.x;
    const int n = blockIdx.x * NT + tid;
    if (n >= N) return;

    float acc[DD];
    #pragma unroll
    for (int d = 0; d < DD; ++d) acc[d] = bn1[d];

    const float* hn = h + (size_t)n * DD;
    for (int k0 = 0; k0 < DD; k0 += 4) {
        const float4 v = *reinterpret_cast<const float4*>(hn + k0);
        const float* w0 = Wn1 + (size_t)(k0 + 0) * DD;
        const float* w1 = Wn1 + (size_t)(k0 + 1) * DD;
        const float* w2 = Wn1 + (size_t)(k0 + 2) * DD;
        const float* w3 = Wn1 + (size_t)(k0 + 3) * DD;
        #pragma unroll
        for (int d = 0; d < DD; ++d) acc[d] = fmaf(v.x, w0[d], acc[d]);
        #pragma unroll
        for (int d = 0; d < DD; ++d) acc[d] = fmaf(v.y, w1[d], acc[d]);
        #pragma unroll
        for (int d = 0; d < DD; ++d) acc[d] = fmaf(v.z, w2[d], acc[d]);
        #pragma unroll
        for (int d = 0; d < DD; ++d) acc[d] = fmaf(v.w, w3[d], acc[d]);
    }
    const float* an = out_h + (size_t)n * DD;
    for (int k0 = 0; k0 < DD; k0 += 4) {
        const float4 v = *reinterpret_cast<const float4*>(an + k0);
        const float* w0 = Wn1 + (size_t)(DD + k0 + 0) * DD;
        const float* w1 = Wn1 + (size_t)(DD + k0 + 1) * DD;
        const float* w2 = Wn1 + (size_t)(DD + k0 + 2) * DD;
        const float* w3 = Wn1 + (size_t)(DD + k0 + 3) * DD;
        #pragma unroll
        for (int d = 0; d < DD; ++d) acc[d] = fmaf(v.x, w0[d], acc[d]);
        #pragma unroll
        for (int d = 0; d < DD; ++d) acc[d] = fmaf(v.y, w1[d], acc[d]);
        #pragma unroll
        for (int d = 0; d < DD; ++d) acc[d] = fmaf(v.z, w2[d], acc[d]);
        #pragma unroll
        for (int d = 0; d < DD; ++d) acc[d] = fmaf(v.w, w3[d], acc[d]);
    }
    #pragma unroll
    for (int d = 0; d < DD; ++d) lds[d * NT + tid] = silu_f(acc[d]);

    float acc2[DD];
    #pragma unroll
    for (int d = 0; d < DD; ++d) acc2[d] = bn2[d];
    for (int k = 0; k < DD; ++k) {
        const float a = lds[k * NT + tid];
        const float* w = Wn2 + (size_t)k * DD;
        #pragma unroll
        for (int d = 0; d < DD; ++d) acc2[d] = fmaf(a, w[d], acc2[d]);
    }

    float* oh = out_h + (size_t)n * DD;
    #pragma unroll
    for (int d = 0; d < DD; ++d) oh[d] = hn[d] + acc2[d];

    const float c = cnt[n];
    const float inv = 1.0f / fmaxf(c, 1.0f);
    #pragma unroll
    for (int j = 0; j < 3; ++j) {
        out_c[(size_t)n * 3 + j] = coord[(size_t)n * 3 + j] + out_c[(size_t)n * 3 + j] * inv;
    }
}

extern "C" void kernel_launch(void* const* d_in, const int* in_sizes, int n_in,
                              void* d_out, int out_size, void* d_ws, size_t ws_size,
                              hipStream_t stream) {
    const float* h     = (const float*)d_in[0];
    const float* coord = (const float*)d_in[1];
    const int*   ei    = (const int*)  d_in[2];
    const float* ea    = (const float*)d_in[3];
    const float* We1   = (const float*)d_in[4];
    const float* be1   = (const float*)d_in[5];
    const float* We2   = (const float*)d_in[6];
    const float* be2   = (const float*)d_in[7];
    const float* Wn1   = (const float*)d_in[8];
    const float* bn1   = (const float*)d_in[9];
    const float* Wn2   = (const float*)d_in[10];
    const float* bn2   = (const float*)d_in[11];
    const float* Wc1   = (const float*)d_in[12];
    const float* bc1   = (const float*)d_in[13];
    const float* Wc2   = (const float*)d_in[14];

    const int N = in_sizes[0] / DD;       // h is [N,64]
    const int E = in_sizes[3] / 2;        // edge_attr is [E,2]

    float* out   = (float*)d_out;
    float* agg_h = out;                         // [N,64] accum -> h_out
    float* agg_c = out + (size_t)N * DD;        // [N,3]  accum -> coord_out
    float* cnt   = (float*)d_ws;                // [N]

    hipMemsetAsync(d_out, 0, sizeof(float) * (size_t)out_size, stream);
    hipMemsetAsync(d_ws, 0, sizeof(float) * (size_t)N, stream);

    const int eblocks = (E + NT - 1) / NT;
    egcl_edge_kernel<<<eblocks, NT, 0, stream>>>(
        h, coord, ei, ea, We1, be1, We2, be2, Wc1, bc1, Wc2,
        agg_h, agg_c, cnt, E);

    const int nblocks = (N + NT - 1) / NT;
    egcl_node_kernel<<<nblocks, NT, 0, stream>>>(
        h, coord, Wn1, bn1, Wn2, bn2, agg_h, agg_c, cnt, N);
}

// Round 2
// 371.192 us; speedup vs baseline: 8.1315x; 8.1315x over previous
//
#include <hip/hip_runtime.h>

#define DD 64
#define NT 256

using s8v   = __attribute__((ext_vector_type(8))) short;   // 8 bf16 (4 VGPRs)
using f32x4 = __attribute__((ext_vector_type(4))) float;   // MFMA C/D

typedef unsigned short ushort_t;
typedef unsigned int   uint_t;

__device__ __forceinline__ float silu_f(float x) {
    return x / (1.0f + __expf(-x));
}

__device__ __forceinline__ unsigned short f2bf(float x) {
    unsigned int u = __float_as_uint(x);
    unsigned int r = (u + 0x7FFFu + ((u >> 16) & 1u)) >> 16;   // RNE
    return (unsigned short)r;
}

#define WAVE_FENCE() do { asm volatile("s_waitcnt lgkmcnt(0)" ::: "memory"); \
                          __builtin_amdgcn_sched_barrier(0); } while (0)

// ---------------------------------------------------------------------------
// Prep 1: h (f32 [N,64]) -> bf16, 8 elems/thread
// ---------------------------------------------------------------------------
__global__ __launch_bounds__(256) void prep_hbf(const float* __restrict__ h,
                                                unsigned short* __restrict__ hbf,
                                                int total8) {
    int t = blockIdx.x * 256 + threadIdx.x;
    if (t >= total8) return;
    const float4 v0 = ((const float4*)h)[t * 2 + 0];
    const float4 v1 = ((const float4*)h)[t * 2 + 1];
    uint4 o;
    o.x = (uint_t)f2bf(v0.x) | ((uint_t)f2bf(v0.y) << 16);
    o.y = (uint_t)f2bf(v0.z) | ((uint_t)f2bf(v0.w) << 16);
    o.z = (uint_t)f2bf(v1.x) | ((uint_t)f2bf(v1.y) << 16);
    o.w = (uint_t)f2bf(v1.z) | ((uint_t)f2bf(v1.w) << 16);
    ((uint4*)hbf)[t] = o;
}

// ---------------------------------------------------------------------------
// Prep 2: pack weights into MFMA B-fragment order (bf16).
// Fragment elem i (0..7) of lane l for (mat,k0,n0):
//   k = k0*32 + 8*(l>>4) + i ,  n = n0*16 + (l&15)
// mats: 0 = We1 rows 0-63, 1 = We1 rows 64-127, 2 = We2, 3 = Wc1.
// Consistent k-mapping on A and B sides => result invariant to the true HW
// k-permutation within a 32-k MFMA call.
// ---------------------------------------------------------------------------
__global__ __launch_bounds__(256) void prep_wfrag(const float* __restrict__ We1,
                                                  const float* __restrict__ We2,
                                                  const float* __restrict__ Wc1,
                                                  unsigned short* __restrict__ wf) {
    int t = blockIdx.x * 256 + threadIdx.x;
    if (t >= 16384) return;
    const int j    = t & 7;
    const int lane = (t >> 3) & 63;
    const int n0   = (t >> 9) & 3;
    const int k0   = (t >> 11) & 1;
    const int mat  = t >> 12;
    const int k = k0 * 32 + ((lane >> 4) * 8) + j;
    const int n = n0 * 16 + (lane & 15);
    float v;
    if      (mat == 0) v = We1[(size_t)k * 64 + n];
    else if (mat == 1) v = We1[(size_t)(64 + k) * 64 + n];
    else if (mat == 2) v = We2[(size_t)k * 64 + n];
    else               v = Wc1[(size_t)k * 64 + n];
    wf[t] = f2bf(v);
}

// ---------------------------------------------------------------------------
// Edge kernel: 4 waves/block, each wave owns a 16-edge tile per iteration.
//   layer1: acc = h[row] @ W1a + h[col] @ W1b   (MFMA, K=64 each)
//           + bias + radial*W[128] + ea0*W[129] + ea1*W[130]  (VALU rank-3)
//   layer2 / coord head: A from LDS-transposed activations.
// Weights live in LDS as pre-packed fragments (no per-k scalar loads).
// ---------------------------------------------------------------------------
__global__ __launch_bounds__(256) void egcl_edge_mfma(
    const unsigned short* __restrict__ hbf,
    const unsigned short* __restrict__ wfG,
    const float* __restrict__ coord,
    const int*   __restrict__ ei,
    const float* __restrict__ ea,
    const float* __restrict__ We1,   // fp32 rows 128..130 for rank-3 part
    const float* __restrict__ be1,
    const float* __restrict__ be2,
    const float* __restrict__ bc1,
    const float* __restrict__ Wc2,
    float* __restrict__ agg_h,
    float* __restrict__ agg_c,
    float* __restrict__ cnt,
    int E, int ngroups, int totalWaves)
{
    __shared__ unsigned short fragLDS[16384];      // 32 KB packed weight frags
    __shared__ unsigned short ldsY[4][16 * 72];    // per-wave [16 edges][64+pad] bf16
    __shared__ float sRad[4][16], sA0[4][16], sA1[4][16], sSc[4][16];
    __shared__ int   sRi[4][16];

    const int tid = threadIdx.x;
    #pragma unroll
    for (int i = 0; i < 8; ++i)
        ((uint4*)fragLDS)[tid + i * 256] = ((const uint4*)wfG)[tid + i * 256];
    __syncthreads();

    const int wid  = tid >> 6;
    const int lane = tid & 63;
    const int l15  = lane & 15;
    const int g    = lane >> 4;

#define LD_WF(mat, k0, n0) \
    (*(const s8v*)(fragLDS + ((((mat)*2 + (k0))*4 + (n0)) * 512) + lane * 8))

    // hoisted per-lane constants (n = n0*16 + l15)
    float be1_c[4], w128_c[4], w129_c[4], w130_c[4], be2_c[4], bc1_c[4], wc2_c[4];
    #pragma unroll
    for (int n0 = 0; n0 < 4; ++n0) {
        const int n = n0 * 16 + l15;
        be1_c[n0]  = be1[n];
        w128_c[n0] = We1[128 * 64 + n];
        w129_c[n0] = We1[129 * 64 + n];
        w130_c[n0] = We1[130 * 64 + n];
        be2_c[n0]  = be2[n];
        bc1_c[n0]  = bc1[n];
        wc2_c[n0]  = Wc2[n];
    }

    const int gw = blockIdx.x * 4 + wid;

    for (int grp = gw; grp < ngroups; grp += totalWaves) {
        const int e0 = grp * 16;
        const int e  = e0 + l15;
        const bool val = (e < E);
        const int eL = val ? e : (E - 1);

        const int ri = ei[eL];
        const int ci = ei[E + eL];
        const float dx = coord[ri * 3 + 0] - coord[ci * 3 + 0];
        const float dy = coord[ri * 3 + 1] - coord[ci * 3 + 1];
        const float dz = coord[ri * 3 + 2] - coord[ci * 3 + 2];
        const float radial = dx * dx + dy * dy + dz * dz;
        if (g == 0) {
            sRad[wid][l15] = radial;
            const float2 a2 = *(const float2*)(ea + (size_t)eL * 2);
            sA0[wid][l15] = a2.x;
            sA1[wid][l15] = a2.y;
            sRi[wid][l15] = ri;
        }

        // A fragments: lane l -> edge row m=l15, k = k0*32 + 8g + i
        const unsigned short* hr = hbf + (size_t)ri * 64;
        const unsigned short* hc = hbf + (size_t)ci * 64;
        const s8v aR0 = *(const s8v*)(hr + g * 8);
        const s8v aR1 = *(const s8v*)(hr + 32 + g * 8);
        const s8v aC0 = *(const s8v*)(hc + g * 8);
        const s8v aC1 = *(const s8v*)(hc + 32 + g * 8);

        f32x4 acc[4];
        #pragma unroll
        for (int n0 = 0; n0 < 4; ++n0) {
            f32x4 a = {0.f, 0.f, 0.f, 0.f};
            a = __builtin_amdgcn_mfma_f32_16x16x32_bf16(aR0, LD_WF(0, 0, n0), a, 0, 0, 0);
            a = __builtin_amdgcn_mfma_f32_16x16x32_bf16(aR1, LD_WF(0, 1, n0), a, 0, 0, 0);
            a = __builtin_amdgcn_mfma_f32_16x16x32_bf16(aC0, LD_WF(1, 0, n0), a, 0, 0, 0);
            a = __builtin_amdgcn_mfma_f32_16x16x32_bf16(aC1, LD_WF(1, 1, n0), a, 0, 0, 0);
            acc[n0] = a;
        }

        WAVE_FENCE();   // sRad/sA0/sA1/sRi visible

        unsigned short* yw = ldsY[wid];
        #pragma unroll
        for (int j = 0; j < 4; ++j) {
            const int m = g * 4 + j;                 // C/D row = edge index
            const float rad = sRad[wid][m];
            const float A0  = sA0[wid][m];
            const float A1  = sA1[wid][m];
            #pragma unroll
            for (int n0 = 0; n0 < 4; ++n0) {
                float y = acc[n0][j] + be1_c[n0] + rad * w128_c[n0]
                        + A0 * w129_c[n0] + A1 * w130_c[n0];
                y = silu_f(y);
                yw[m * 72 + n0 * 16 + l15] = f2bf(y);
            }
        }

        WAVE_FENCE();   // ldsY (layer1 activations) visible

        const unsigned short* yrow = yw + l15 * 72;
        float y2a[4][4];
        {
            const s8v a0 = *(const s8v*)(yrow + g * 8);
            const s8v a1 = *(const s8v*)(yrow + 32 + g * 8);
            #pragma unroll
            for (int n0 = 0; n0 < 4; ++n0) {
                f32x4 a = {0.f, 0.f, 0.f, 0.f};
                a = __builtin_amdgcn_mfma_f32_16x16x32_bf16(a0, LD_WF(2, 0, n0), a, 0, 0, 0);
                a = __builtin_amdgcn_mfma_f32_16x16x32_bf16(a1, LD_WF(2, 1, n0), a, 0, 0, 0);
                #pragma unroll
                for (int j = 0; j < 4; ++j)
                    y2a[n0][j] = silu_f(a[j] + be2_c[n0]);
            }
            // write edge_feat (bf16) for coord head A-operand
            #pragma unroll
            for (int j = 0; j < 4; ++j) {
                const int m = g * 4 + j;
                #pragma unroll
                for (int n0 = 0; n0 < 4; ++n0)
                    yw[m * 72 + n0 * 16 + l15] = f2bf(y2a[n0][j]);
            }
            // coalesced agg_h scatter: 16 lanes x contiguous 64B per (j,n0)
            #pragma unroll
            for (int j = 0; j < 4; ++j) {
                if (e0 + g * 4 + j < E) {
                    const int r2 = sRi[wid][g * 4 + j];
                    float* bp = agg_h + (size_t)r2 * 64 + l15;
                    #pragma unroll
                    for (int n0 = 0; n0 < 4; ++n0)
                        atomicAdd(bp + n0 * 16, y2a[n0][j]);
                }
            }
        }

        WAVE_FENCE();   // ldsY (edge_feat) visible

        {
            const s8v a0 = *(const s8v*)(yrow + g * 8);
            const s8v a1 = *(const s8v*)(yrow + 32 + g * 8);
            float p[4] = {0.f, 0.f, 0.f, 0.f};
            #pragma unroll
            for (int n0 = 0; n0 < 4; ++n0) {
                f32x4 a = {0.f, 0.f, 0.f, 0.f};
                a = __builtin_amdgcn_mfma_f32_16x16x32_bf16(a0, LD_WF(3, 0, n0), a, 0, 0, 0);
                a = __builtin_amdgcn_mfma_f32_16x16x32_bf16(a1, LD_WF(3, 1, n0), a, 0, 0, 0);
                #pragma unroll
                for (int j = 0; j < 4; ++j)
                    p[j] += silu_f(a[j] + bc1_c[n0]) * wc2_c[n0];
            }
            // reduce over the 16 lanes of this lane-group (n dimension)
            #pragma unroll
            for (int j = 0; j < 4; ++j) {
                p[j] += __shfl_xor(p[j], 1, 64);
                p[j] += __shfl_xor(p[j], 2, 64);
                p[j] += __shfl_xor(p[j], 4, 64);
                p[j] += __shfl_xor(p[j], 8, 64);
            }
            if (l15 == 0) {
                #pragma unroll
                for (int j = 0; j < 4; ++j) sSc[wid][g * 4 + j] = p[j];
            }
        }

        WAVE_FENCE();   // sSc visible

        {
            const float sc = sSc[wid][l15];
            const float dcomp = (g == 0) ? dx : (g == 1) ? dy : dz;
            float t = dcomp * sc;
            t = fminf(fmaxf(t, -100.0f), 100.0f);
            if (val) {
                if (g < 3) atomicAdd(agg_c + (size_t)ri * 3 + g, t);
                else       atomicAdd(cnt + ri, 1.0f);
            }
        }
    }
#undef LD_WF
}

// ---------------------------------------------------------------------------
// Node kernel (unchanged from round 1, fp32): finalizes h_out / coord_out.
// ---------------------------------------------------------------------------
__global__ __launch_bounds__(NT) void egcl_node_kernel(
    const float* __restrict__ h,
    const float* __restrict__ coord,
    const float* __restrict__ Wn1, const float* __restrict__ bn1,
    const float* __restrict__ Wn2, const float* __restrict__ bn2,
    float* __restrict__ out_h,
    float* __restrict__ out_c,
    const float* __restrict__ cnt,
    int N)
{
    __shared__ float lds[DD * NT];
    const int tid = threadIdx.x;
    const int n = blockIdx.x * NT + tid;
    if (n >= N) return;

    float acc[DD];
    #pragma unroll
    for (int d = 0; d < DD; ++d) acc[d] = bn1[d];

    const float* hn = h + (size_t)n * DD;
    for (int k0 = 0; k0 < DD; k0 += 4) {
        const float4 v = *reinterpret_cast<const float4*>(hn + k0);
        const float* w0 = Wn1 + (size_t)(k0 + 0) * DD;
        const float* w1 = Wn1 + (size_t)(k0 + 1) * DD;
        const float* w2 = Wn1 + (size_t)(k0 + 2) * DD;
        const float* w3 = Wn1 + (size_t)(k0 + 3) * DD;
        #pragma unroll
        for (int d = 0; d < DD; ++d) acc[d] = fmaf(v.x, w0[d], acc[d]);
        #pragma unroll
        for (int d = 0; d < DD; ++d) acc[d] = fmaf(v.y, w1[d], acc[d]);
        #pragma unroll
        for (int d = 0; d < DD; ++d) acc[d] = fmaf(v.z, w2[d], acc[d]);
        #pragma unroll
        for (int d = 0; d < DD; ++d) acc[d] = fmaf(v.w, w3[d], acc[d]);
    }
    const float* an = out_h + (size_t)n * DD;
    for (int k0 = 0; k0 < DD; k0 += 4) {
        const float4 v = *reinterpret_cast<const float4*>(an + k0);
        const float* w0 = Wn1 + (size_t)(DD + k0 + 0) * DD;
        const float* w1 = Wn1 + (size_t)(DD + k0 + 1) * DD;
        const float* w2 = Wn1 + (size_t)(DD + k0 + 2) * DD;
        const float* w3 = Wn1 + (size_t)(DD + k0 + 3) * DD;
        #pragma unroll
        for (int d = 0; d < DD; ++d) acc[d] = fmaf(v.x, w0[d], acc[d]);
        #pragma unroll
        for (int d = 0; d < DD; ++d) acc[d] = fmaf(v.y, w1[d], acc[d]);
        #pragma unroll
        for (int d = 0; d < DD; ++d) acc[d] = fmaf(v.z, w2[d], acc[d]);
        #pragma unroll
        for (int d = 0; d < DD; ++d) acc[d] = fmaf(v.w, w3[d], acc[d]);
    }
    #pragma unroll
    for (int d = 0; d < DD; ++d) lds[d * NT + tid] = silu_f(acc[d]);

    float acc2[DD];
    #pragma unroll
    for (int d = 0; d < DD; ++d) acc2[d] = bn2[d];
    for (int k = 0; k < DD; ++k) {
        const float a = lds[k * NT + tid];
        const float* w = Wn2 + (size_t)k * DD;
        #pragma unroll
        for (int d = 0; d < DD; ++d) acc2[d] = fmaf(a, w[d], acc2[d]);
    }

    float* oh = out_h + (size_t)n * DD;
    #pragma unroll
    for (int d = 0; d < DD; ++d) oh[d] = hn[d] + acc2[d];

    const float c = cnt[n];
    const float inv = 1.0f / fmaxf(c, 1.0f);
    #pragma unroll
    for (int j = 0; j < 3; ++j) {
        out_c[(size_t)n * 3 + j] = coord[(size_t)n * 3 + j] + out_c[(size_t)n * 3 + j] * inv;
    }
}

extern "C" void kernel_launch(void* const* d_in, const int* in_sizes, int n_in,
                              void* d_out, int out_size, void* d_ws, size_t ws_size,
                              hipStream_t stream) {
    const float* h     = (const float*)d_in[0];
    const float* coord = (const float*)d_in[1];
    const int*   ei    = (const int*)  d_in[2];
    const float* ea    = (const float*)d_in[3];
    const float* We1   = (const float*)d_in[4];
    const float* be1   = (const float*)d_in[5];
    const float* We2   = (const float*)d_in[6];
    const float* be2   = (const float*)d_in[7];
    const float* Wn1   = (const float*)d_in[8];
    const float* bn1   = (const float*)d_in[9];
    const float* Wn2   = (const float*)d_in[10];
    const float* bn2   = (const float*)d_in[11];
    const float* Wc1   = (const float*)d_in[12];
    const float* bc1   = (const float*)d_in[13];
    const float* Wc2   = (const float*)d_in[14];

    const int N = in_sizes[0] / DD;     // h is [N,64]
    const int E = in_sizes[3] / 2;      // edge_attr is [E,2]

    float* out   = (float*)d_out;
    float* agg_h = out;                        // [N,64] accum -> h_out
    float* agg_c = out + (size_t)N * DD;       // [N,3]  accum -> coord_out

    // workspace layout
    unsigned short* hbf = (unsigned short*)d_ws;                 // N*64 bf16
    const size_t o_wf  = (size_t)N * DD * 2;                     // bytes
    unsigned short* wf  = (unsigned short*)((char*)d_ws + o_wf); // 16384 bf16
    const size_t o_cnt = o_wf + 16384 * 2;
    float* cnt = (float*)((char*)d_ws + o_cnt);                  // N floats

    hipMemsetAsync(d_out, 0, sizeof(float) * (size_t)out_size, stream);
    hipMemsetAsync((void*)cnt, 0, sizeof(float) * (size_t)N, stream);

    // prep
    const int total8 = N * DD / 8;
    prep_hbf<<<(total8 + 255) / 256, 256, 0, stream>>>(h, hbf, total8);
    prep_wfrag<<<64, 256, 0, stream>>>(We1, We2, Wc1, wf);

    // edge
    const int ngroups = (E + 15) / 16;
    const int eblocks = 1024;
    const int totalWaves = eblocks * 4;
    egcl_edge_mfma<<<eblocks, 256, 0, stream>>>(
        hbf, wf, coord, ei, ea, We1, be1, be2, bc1, Wc2,
        agg_h, agg_c, cnt, E, ngroups, totalWaves);

    // node
    const int nblocks = (N + NT - 1) / NT;
    egcl_node_kernel<<<nblocks, NT, 0, stream>>>(
        h, coord, Wn1, bn1, Wn2, bn2, agg_h, agg_c, cnt, N);
}

// Round 3
// 347.072 us; speedup vs baseline: 8.6966x; 1.0695x over previous
//
#include <hip/hip_runtime.h>

#define DD 64
#define NTE 512   // edge kernel: 8 waves/block
#define NT 256

using s8v   = __attribute__((ext_vector_type(8))) short;   // 8 bf16 (4 VGPRs)
using f32x4 = __attribute__((ext_vector_type(4))) float;   // MFMA C/D

typedef unsigned int uint_t;

__device__ __forceinline__ float silu_f(float x) {
    return x / (1.0f + __expf(-x));
}

__device__ __forceinline__ unsigned short f2bf(float x) {
    unsigned int u = __float_as_uint(x);
    unsigned int r = (u + 0x7FFFu + ((u >> 16) & 1u)) >> 16;   // RNE
    return (unsigned short)r;
}

#define WAVE_FENCE() do { asm volatile("s_waitcnt lgkmcnt(0)" ::: "memory"); \
                          __builtin_amdgcn_sched_barrier(0); } while (0)

// ---------------------------------------------------------------------------
// Prep 1: h (f32 [N,64]) -> bf16
// ---------------------------------------------------------------------------
__global__ __launch_bounds__(256) void prep_hbf(const float* __restrict__ h,
                                                unsigned short* __restrict__ hbf,
                                                int total8) {
    int t = blockIdx.x * 256 + threadIdx.x;
    if (t >= total8) return;
    const float4 v0 = ((const float4*)h)[t * 2 + 0];
    const float4 v1 = ((const float4*)h)[t * 2 + 1];
    uint4 o;
    o.x = (uint_t)f2bf(v0.x) | ((uint_t)f2bf(v0.y) << 16);
    o.y = (uint_t)f2bf(v0.z) | ((uint_t)f2bf(v0.w) << 16);
    o.z = (uint_t)f2bf(v1.x) | ((uint_t)f2bf(v1.y) << 16);
    o.w = (uint_t)f2bf(v1.z) | ((uint_t)f2bf(v1.w) << 16);
    ((uint4*)hbf)[t] = o;
}

// ---------------------------------------------------------------------------
// Prep 2: pack weights into MFMA B-fragment order (bf16).
//   frag elem i of lane l for (mat,k0,n0):  k = k0*32 + 8*(l>>4) + i
//                                           n = n0*16 + (l&15)
// mats: 0 = We1[0:64], 1 = We1[64:128], 2 = We2, 3 = Wc1.
// ---------------------------------------------------------------------------
__global__ __launch_bounds__(256) void prep_wfrag(const float* __restrict__ We1,
                                                  const float* __restrict__ We2,
                                                  const float* __restrict__ Wc1,
                                                  unsigned short* __restrict__ wf) {
    int t = blockIdx.x * 256 + threadIdx.x;
    if (t >= 16384) return;
    const int j    = t & 7;
    const int lane = (t >> 3) & 63;
    const int n0   = (t >> 9) & 3;
    const int k0   = (t >> 11) & 1;
    const int mat  = t >> 12;
    const int k = k0 * 32 + ((lane >> 4) * 8) + j;
    const int n = n0 * 16 + (lane & 15);
    float v;
    if      (mat == 0) v = We1[(size_t)k * 64 + n];
    else if (mat == 1) v = We1[(size_t)(64 + k) * 64 + n];
    else if (mat == 2) v = We2[(size_t)k * 64 + n];
    else               v = Wc1[(size_t)k * 64 + n];
    wf[t] = f2bf(v);
}

// ---------------------------------------------------------------------------
// Edge kernel: 8 waves/block, 16-edge tile per wave iteration, 2-stage
// global prefetch (next tile's indices + h-fragments + coord/ea in flight
// during current tile's compute/atomics).
// ---------------------------------------------------------------------------
__global__ __launch_bounds__(NTE, 4) void egcl_edge_mfma(
    const unsigned short* __restrict__ hbf,
    const unsigned short* __restrict__ wfG,
    const float* __restrict__ coord,
    const int*   __restrict__ ei,
    const float* __restrict__ ea,
    const float* __restrict__ We1,   // fp32 rows 128..130 (rank-3 part)
    const float* __restrict__ be1,
    const float* __restrict__ be2,
    const float* __restrict__ bc1,
    const float* __restrict__ Wc2,
    float* __restrict__ agg_h,
    float* __restrict__ agg_c,
    float* __restrict__ cnt,
    int E, int ngroups, int totalWaves)
{
    __shared__ unsigned short fragLDS[16384];      // 32 KB weight frags
    __shared__ unsigned short ldsY[8][16 * 72];    // per-wave [16][64+8] bf16
    __shared__ float sRad[8][16], sA0[8][16], sA1[8][16], sSc[8][16];
    __shared__ int   sRi[8][16];

    const int tid = threadIdx.x;
    #pragma unroll
    for (int i = 0; i < 4; ++i)
        ((uint4*)fragLDS)[tid + i * 512] = ((const uint4*)wfG)[tid + i * 512];
    __syncthreads();

    const int wid  = tid >> 6;
    const int lane = tid & 63;
    const int l15  = lane & 15;
    const int g    = lane >> 4;

#define LD_WF(mat, k0, n0) \
    (*(const s8v*)(fragLDS + ((((mat)*2 + (k0))*4 + (n0)) * 512) + lane * 8))

    // hoisted per-lane constants (n = n0*16 + l15)
    float be1_c[4], w128_c[4], w129_c[4], w130_c[4], be2_c[4], bc1_c[4], wc2_c[4];
    #pragma unroll
    for (int n0 = 0; n0 < 4; ++n0) {
        const int n = n0 * 16 + l15;
        be1_c[n0]  = be1[n];
        w128_c[n0] = We1[128 * 64 + n];
        w129_c[n0] = We1[129 * 64 + n];
        w130_c[n0] = We1[130 * 64 + n];
        be2_c[n0]  = be2[n];
        bc1_c[n0]  = bc1[n];
        wc2_c[n0]  = Wc2[n];
    }

    int grp = blockIdx.x * 8 + wid;
    if (grp >= ngroups) return;

    // -------- preamble: stage-in for the first group --------
    int ri, ci;
    float crx, cry, crz, ccx, ccy, ccz, ea0v, ea1v;
    s8v aR0, aR1, aC0, aC1;
    {
        const int e  = grp * 16 + l15;
        const int eL = (e < E) ? e : (E - 1);
        ri = ei[eL];
        ci = ei[E + eL];
        const unsigned short* hr = hbf + (size_t)ri * 64;
        const unsigned short* hc = hbf + (size_t)ci * 64;
        aR0 = *(const s8v*)(hr + g * 8);
        aR1 = *(const s8v*)(hr + 32 + g * 8);
        aC0 = *(const s8v*)(hc + g * 8);
        aC1 = *(const s8v*)(hc + 32 + g * 8);
        crx = coord[ri * 3 + 0]; cry = coord[ri * 3 + 1]; crz = coord[ri * 3 + 2];
        ccx = coord[ci * 3 + 0]; ccy = coord[ci * 3 + 1]; ccz = coord[ci * 3 + 2];
        const float2 a2 = *(const float2*)(ea + (size_t)eL * 2);
        ea0v = a2.x; ea1v = a2.y;
    }

    for (; grp < ngroups; grp += totalWaves) {
        const int nextGrp = grp + totalWaves;
        const bool hasNext = nextGrp < ngroups;

        // issue next-group index loads early (vmcnt; covered by layer1/2)
        int nri, nci, neL;
        {
            const int ne = hasNext ? nextGrp * 16 + l15 : 0;
            neL = (ne < E) ? ne : (E - 1);
            nri = ei[neL];
            nci = ei[E + neL];
        }

        const int e0  = grp * 16;
        const bool val = (e0 + l15 < E);
        const float dx = crx - ccx, dy = cry - ccy, dz = crz - ccz;
        const float radial = dx * dx + dy * dy + dz * dz;
        if (g == 0) {
            sRad[wid][l15] = radial;
            sA0[wid][l15]  = ea0v;
            sA1[wid][l15]  = ea1v;
            sRi[wid][l15]  = ri;
        }

        // ---- layer 1 MFMAs (K=64 row-part + K=64 col-part) ----
        f32x4 acc[4];
        #pragma unroll
        for (int n0 = 0; n0 < 4; ++n0) {
            f32x4 a = {0.f, 0.f, 0.f, 0.f};
            a = __builtin_amdgcn_mfma_f32_16x16x32_bf16(aR0, LD_WF(0, 0, n0), a, 0, 0, 0);
            a = __builtin_amdgcn_mfma_f32_16x16x32_bf16(aR1, LD_WF(0, 1, n0), a, 0, 0, 0);
            a = __builtin_amdgcn_mfma_f32_16x16x32_bf16(aC0, LD_WF(1, 0, n0), a, 0, 0, 0);
            a = __builtin_amdgcn_mfma_f32_16x16x32_bf16(aC1, LD_WF(1, 1, n0), a, 0, 0, 0);
            acc[n0] = a;
        }

        WAVE_FENCE();   // sRad/sA0/sA1/sRi visible (wave-local)

        // ---- layer-1 epilogue: rank-3 update + bias + silu -> ldsY ----
        unsigned short* yw = ldsY[wid];
        #pragma unroll
        for (int j = 0; j < 4; ++j) {
            const int m = g * 4 + j;
            const float rad = sRad[wid][m];
            const float A0  = sA0[wid][m];
            const float A1  = sA1[wid][m];
            #pragma unroll
            for (int n0 = 0; n0 < 4; ++n0) {
                float y = acc[n0][j] + be1_c[n0] + rad * w128_c[n0]
                        + A0 * w129_c[n0] + A1 * w130_c[n0];
                yw[m * 72 + n0 * 16 + l15] = f2bf(silu_f(y));
            }
        }

        // ---- prefetch next group's gathers (pure vmcnt; survives fences) ----
        s8v naR0, naR1, naC0, naC1;
        float ncrx, ncry, ncrz, nccx, nccy, nccz, nea0, nea1;
        {
            const unsigned short* hr = hbf + (size_t)nri * 64;
            const unsigned short* hc = hbf + (size_t)nci * 64;
            naR0 = *(const s8v*)(hr + g * 8);
            naR1 = *(const s8v*)(hr + 32 + g * 8);
            naC0 = *(const s8v*)(hc + g * 8);
            naC1 = *(const s8v*)(hc + 32 + g * 8);
            ncrx = coord[nri * 3 + 0]; ncry = coord[nri * 3 + 1]; ncrz = coord[nri * 3 + 2];
            nccx = coord[nci * 3 + 0]; nccy = coord[nci * 3 + 1]; nccz = coord[nci * 3 + 2];
            const float2 a2 = *(const float2*)(ea + (size_t)neL * 2);
            nea0 = a2.x; nea1 = a2.y;
        }

        WAVE_FENCE();   // ldsY (layer-1 activations) visible

        // ---- layer 2 + agg_h scatter (per-n0 to keep lifetimes short) ----
        const unsigned short* yrow = yw + l15 * 72;
        {
            const s8v a0 = *(const s8v*)(yrow + g * 8);
            const s8v a1 = *(const s8v*)(yrow + 32 + g * 8);
            #pragma unroll
            for (int n0 = 0; n0 < 4; ++n0) {
                f32x4 a = {0.f, 0.f, 0.f, 0.f};
                a = __builtin_amdgcn_mfma_f32_16x16x32_bf16(a0, LD_WF(2, 0, n0), a, 0, 0, 0);
                a = __builtin_amdgcn_mfma_f32_16x16x32_bf16(a1, LD_WF(2, 1, n0), a, 0, 0, 0);
                float y2[4];
                #pragma unroll
                for (int j = 0; j < 4; ++j) {
                    y2[j] = silu_f(a[j] + be2_c[n0]);
                    yw[(g * 4 + j) * 72 + n0 * 16 + l15] = f2bf(y2[j]);
                }
                #pragma unroll
                for (int j = 0; j < 4; ++j) {
                    if (e0 + g * 4 + j < E) {
                        const int r2 = sRi[wid][g * 4 + j];
                        atomicAdd(agg_h + (size_t)r2 * 64 + n0 * 16 + l15, y2[j]);
                    }
                }
            }
        }

        WAVE_FENCE();   // ldsY (edge_feat) visible

        // ---- coord head: 64 -> 64 -> 1, reduce over n within lane-group ----
        {
            const s8v a0 = *(const s8v*)(yrow + g * 8);
            const s8v a1 = *(const s8v*)(yrow + 32 + g * 8);
            float p[4] = {0.f, 0.f, 0.f, 0.f};
            #pragma unroll
            for (int n0 = 0; n0 < 4; ++n0) {
                f32x4 a = {0.f, 0.f, 0.f, 0.f};
                a = __builtin_amdgcn_mfma_f32_16x16x32_bf16(a0, LD_WF(3, 0, n0), a, 0, 0, 0);
                a = __builtin_amdgcn_mfma_f32_16x16x32_bf16(a1, LD_WF(3, 1, n0), a, 0, 0, 0);
                #pragma unroll
                for (int j = 0; j < 4; ++j)
                    p[j] += silu_f(a[j] + bc1_c[n0]) * wc2_c[n0];
            }
            #pragma unroll
            for (int j = 0; j < 4; ++j) {
                p[j] += __shfl_xor(p[j], 1, 64);
                p[j] += __shfl_xor(p[j], 2, 64);
                p[j] += __shfl_xor(p[j], 4, 64);
                p[j] += __shfl_xor(p[j], 8, 64);
            }
            if (l15 == 0) {
                #pragma unroll
                for (int j = 0; j < 4; ++j) sSc[wid][g * 4 + j] = p[j];
            }
        }

        WAVE_FENCE();   // sSc visible

        // ---- coord scatter ----
        {
            const float sc = sSc[wid][l15];
            const float dcomp = (g == 0) ? dx : (g == 1) ? dy : dz;
            float t = dcomp * sc;
            t = fminf(fmaxf(t, -100.0f), 100.0f);
            if (val) {
                if (g < 3) atomicAdd(agg_c + (size_t)ri * 3 + g, t);
                else       atomicAdd(cnt + ri, 1.0f);
            }
        }

        // ---- rotate pipeline ----
        ri = nri; ci = nci;
        aR0 = naR0; aR1 = naR1; aC0 = naC0; aC1 = naC1;
        crx = ncrx; cry = ncry; crz = ncrz;
        ccx = nccx; ccy = nccy; ccz = nccz;
        ea0v = nea0; ea1v = nea1;
    }
#undef LD_WF
}

// ---------------------------------------------------------------------------
// Node kernel (fp32): finalizes h_out / coord_out.
// ---------------------------------------------------------------------------
__global__ __launch_bounds__(NT) void egcl_node_kernel(
    const float* __restrict__ h,
    const float* __restrict__ coord,
    const float* __restrict__ Wn1, const float* __restrict__ bn1,
    const float* __restrict__ Wn2, const float* __restrict__ bn2,
    float* __restrict__ out_h,
    float* __restrict__ out_c,
    const float* __restrict__ cnt,
    int N)
{
    __shared__ float lds[DD * NT];
    const int tid = threadIdx.x;
    const int n = blockIdx.x * NT + tid;
    if (n >= N) return;

    float acc[DD];
    #pragma unroll
    for (int d = 0; d < DD; ++d) acc[d] = bn1[d];

    const float* hn = h + (size_t)n * DD;
    for (int k0 = 0; k0 < DD; k0 += 4) {
        const float4 v = *reinterpret_cast<const float4*>(hn + k0);
        const float* w0 = Wn1 + (size_t)(k0 + 0) * DD;
        const float* w1 = Wn1 + (size_t)(k0 + 1) * DD;
        const float* w2 = Wn1 + (size_t)(k0 + 2) * DD;
        const float* w3 = Wn1 + (size_t)(k0 + 3) * DD;
        #pragma unroll
        for (int d = 0; d < DD; ++d) acc[d] = fmaf(v.x, w0[d], acc[d]);
        #pragma unroll
        for (int d = 0; d < DD; ++d) acc[d] = fmaf(v.y, w1[d], acc[d]);
        #pragma unroll
        for (int d = 0; d < DD; ++d) acc[d] = fmaf(v.z, w2[d], acc[d]);
        #pragma unroll
        for (int d = 0; d < DD; ++d) acc[d] = fmaf(v.w, w3[d], acc[d]);
    }
    const float* an = out_h + (size_t)n * DD;
    for (int k0 = 0; k0 < DD; k0 += 4) {
        const float4 v = *reinterpret_cast<const float4*>(an + k0);
        const float* w0 = Wn1 + (size_t)(DD + k0 + 0) * DD;
        const float* w1 = Wn1 + (size_t)(DD + k0 + 1) * DD;
        const float* w2 = Wn1 + (size_t)(DD + k0 + 2) * DD;
        const float* w3 = Wn1 + (size_t)(DD + k0 + 3) * DD;
        #pragma unroll
        for (int d = 0; d < DD; ++d) acc[d] = fmaf(v.x, w0[d], acc[d]);
        #pragma unroll
        for (int d = 0; d < DD; ++d) acc[d] = fmaf(v.y, w1[d], acc[d]);
        #pragma unroll
        for (int d = 0; d < DD; ++d) acc[d] = fmaf(v.z, w2[d], acc[d]);
        #pragma unroll
        for (int d = 0; d < DD; ++d) acc[d] = fmaf(v.w, w3[d], acc[d]);
    }
    #pragma unroll
    for (int d = 0; d < DD; ++d) lds[d * NT + tid] = silu_f(acc[d]);

    float acc2[DD];
    #pragma unroll
    for (int d = 0; d < DD; ++d) acc2[d] = bn2[d];
    for (int k = 0; k < DD; ++k) {
        const float a = lds[k * NT + tid];
        const float* w = Wn2 + (size_t)k * DD;
        #pragma unroll
        for (int d = 0; d < DD; ++d) acc2[d] = fmaf(a, w[d], acc2[d]);
    }

    float* oh = out_h + (size_t)n * DD;
    #pragma unroll
    for (int d = 0; d < DD; ++d) oh[d] = hn[d] + acc2[d];

    const float c = cnt[n];
    const float inv = 1.0f / fmaxf(c, 1.0f);
    #pragma unroll
    for (int j = 0; j < 3; ++j) {
        out_c[(size_t)n * 3 + j] = coord[(size_t)n * 3 + j] + out_c[(size_t)n * 3 + j] * inv;
    }
}

extern "C" void kernel_launch(void* const* d_in, const int* in_sizes, int n_in,
                              void* d_out, int out_size, void* d_ws, size_t ws_size,
                              hipStream_t stream) {
    const float* h     = (const float*)d_in[0];
    const float* coord = (const float*)d_in[1];
    const int*   ei    = (const int*)  d_in[2];
    const float* ea    = (const float*)d_in[3];
    const float* We1   = (const float*)d_in[4];
    const float* be1   = (const float*)d_in[5];
    const float* We2   = (const float*)d_in[6];
    const float* be2   = (const float*)d_in[7];
    const float* Wn1   = (const float*)d_in[8];
    const float* bn1   = (const float*)d_in[9];
    const float* Wn2   = (const float*)d_in[10];
    const float* bn2   = (const float*)d_in[11];
    const float* Wc1   = (const float*)d_in[12];
    const float* bc1   = (const float*)d_in[13];
    const float* Wc2   = (const float*)d_in[14];

    const int N = in_sizes[0] / DD;     // h is [N,64]
    const int E = in_sizes[3] / 2;      // edge_attr is [E,2]

    float* out   = (float*)d_out;
    float* agg_h = out;                        // [N,64] accum -> h_out
    float* agg_c = out + (size_t)N * DD;       // [N,3]  accum -> coord_out

    // workspace layout
    unsigned short* hbf = (unsigned short*)d_ws;                 // N*64 bf16
    const size_t o_wf  = (size_t)N * DD * 2;                     // bytes
    unsigned short* wf  = (unsigned short*)((char*)d_ws + o_wf); // 16384 bf16
    const size_t o_cnt = o_wf + 16384 * 2;
    float* cnt = (float*)((char*)d_ws + o_cnt);                  // N floats

    hipMemsetAsync(d_out, 0, sizeof(float) * (size_t)out_size, stream);
    hipMemsetAsync((void*)cnt, 0, sizeof(float) * (size_t)N, stream);

    // prep
    const int total8 = N * DD / 8;
    prep_hbf<<<(total8 + 255) / 256, 256, 0, stream>>>(h, hbf, total8);
    prep_wfrag<<<64, 256, 0, stream>>>(We1, We2, Wc1, wf);

    // edge: 512 blocks x 8 waves (2 blocks/CU resident)
    const int ngroups = (E + 15) / 16;
    const int eblocks = 512;
    const int totalWaves = eblocks * 8;
    egcl_edge_mfma<<<eblocks, NTE, 0, stream>>>(
        hbf, wf, coord, ei, ea, We1, be1, be2, bc1, Wc2,
        agg_h, agg_c, cnt, E, ngroups, totalWaves);

    // node
    const int nblocks = (N + NT - 1) / NT;
    egcl_node_kernel<<<nblocks, NT, 0, stream>>>(
        h, coord, Wn1, bn1, Wn2, bn2, agg_h, agg_c, cnt, N);
}

// Round 4
// 255.295 us; speedup vs baseline: 11.8230x; 1.3595x over previous
//
#include <hip/hip_runtime.h>

#define DD 64
#define NTE 512
#define SLOTMAX 64

using s8v   = __attribute__((ext_vector_type(8))) short;   // 8 bf16 (4 VGPRs)
using f32x4 = __attribute__((ext_vector_type(4))) float;   // MFMA C/D

typedef unsigned int   uint_t;
typedef unsigned short ushort_t;

__device__ __forceinline__ float silu_f(float x) {
    return x / (1.0f + __expf(-x));
}
__device__ __forceinline__ float clamp100(float x) {
    return fminf(fmaxf(x, -100.0f), 100.0f);
}
__device__ __forceinline__ unsigned short f2bf(float x) {
    unsigned int u = __float_as_uint(x);
    return (unsigned short)((u + 0x7FFFu + ((u >> 16) & 1u)) >> 16);   // RNE
}

#define WAVE_FENCE() do { asm volatile("s_waitcnt lgkmcnt(0)" ::: "memory"); \
                          __builtin_amdgcn_sched_barrier(0); } while (0)

// ---------------------------------------------------------------------------
// Combined prep: [histBlocks) histogram+slot-assign | [hbfBlocks) h->bf16 |
// [wfBlocks) weight-fragment packing (7 mats: We1a,We1b,We2,Wc1,Wn1a,Wn1b,Wn2)
//   frag elem i of lane l for (mat,k0,n0):  k = k0*32 + 8*(l>>4) + i
//                                           n = n0*16 + (l&15)
// ---------------------------------------------------------------------------
__global__ __launch_bounds__(256) void prep_all(
    const float* __restrict__ h,
    const float* __restrict__ We1, const float* __restrict__ We2,
    const float* __restrict__ Wc1,
    const float* __restrict__ Wn1, const float* __restrict__ Wn2,
    const int*   __restrict__ ei,
    ushort_t* __restrict__ hbf,
    ushort_t* __restrict__ wf,
    int* __restrict__ cnt_i,
    int* __restrict__ slots,
    int E, int total8, int histBlocks, int hbfBlocks)
{
    const int b = blockIdx.x;
    if (b < histBlocks) {
        const int e = b * 256 + threadIdx.x;
        if (e < E) {
            const int r = ei[e];
            const int s = atomicAdd(&cnt_i[r], 1);
            if (s < SLOTMAX) slots[(size_t)r * SLOTMAX + s] = e;
        }
    } else if (b < histBlocks + hbfBlocks) {
        const int t = (b - histBlocks) * 256 + threadIdx.x;
        if (t < total8) {
            const float4 v0 = ((const float4*)h)[t * 2 + 0];
            const float4 v1 = ((const float4*)h)[t * 2 + 1];
            uint4 o;
            o.x = (uint_t)f2bf(v0.x) | ((uint_t)f2bf(v0.y) << 16);
            o.y = (uint_t)f2bf(v0.z) | ((uint_t)f2bf(v0.w) << 16);
            o.z = (uint_t)f2bf(v1.x) | ((uint_t)f2bf(v1.y) << 16);
            o.w = (uint_t)f2bf(v1.z) | ((uint_t)f2bf(v1.w) << 16);
            ((uint4*)hbf)[t] = o;
        }
    } else {
        const int t = (b - histBlocks - hbfBlocks) * 256 + threadIdx.x;
        if (t < 7 * 4096) {
            const int j    = t & 7;
            const int lane = (t >> 3) & 63;
            const int n0   = (t >> 9) & 3;
            const int k0   = (t >> 11) & 1;
            const int mat  = t >> 12;
            const int k = k0 * 32 + ((lane >> 4) * 8) + j;
            const int n = n0 * 16 + (lane & 15);
            float v;
            if      (mat == 0) v = We1[(size_t)k * 64 + n];
            else if (mat == 1) v = We1[(size_t)(64 + k) * 64 + n];
            else if (mat == 2) v = We2[(size_t)k * 64 + n];
            else if (mat == 3) v = Wc1[(size_t)k * 64 + n];
            else if (mat == 4) v = Wn1[(size_t)k * 64 + n];
            else if (mat == 5) v = Wn1[(size_t)(64 + k) * 64 + n];
            else               v = Wn2[(size_t)k * 64 + n];
            wf[t] = f2bf(v);
        }
    }
}

// ---------------------------------------------------------------------------
// Edge kernel: one WAVE per NODE. Processes the node's edges (slot list) in
// 16-edge MFMA tiles; row-half of layer1 precomputed once per node; agg_h /
// trans accumulate in registers; plain coalesced stores. NO atomics.
// ---------------------------------------------------------------------------
__global__ __launch_bounds__(NTE, 4) void egcl_edge(
    const ushort_t* __restrict__ hbf,
    const ushort_t* __restrict__ wfG,
    const float* __restrict__ coord,
    const int*   __restrict__ ei,
    const float* __restrict__ ea,
    const float* __restrict__ We1,   // fp32 rows 128..130 (rank-3 part)
    const float* __restrict__ be1,
    const float* __restrict__ be2,
    const float* __restrict__ bc1,
    const float* __restrict__ Wc2,
    const int* __restrict__ cnt_i,
    const int* __restrict__ slots,
    ushort_t* __restrict__ aggbf,    // [N,64] bf16
    float* __restrict__ coord_out,   // [N,3]
    int N, int E, int totalWaves)
{
    __shared__ ushort_t fragLDS[16384];        // mats 0..3, 32 KB
    __shared__ ushort_t ldsY[8][16 * 72];      // per-wave transpose tile

    const int tid = threadIdx.x;
    #pragma unroll
    for (int i = 0; i < 4; ++i)
        ((uint4*)fragLDS)[tid + i * 512] = ((const uint4*)wfG)[tid + i * 512];
    __syncthreads();

    const int wid  = tid >> 6;
    const int lane = tid & 63;
    const int l15  = lane & 15;
    const int g    = lane >> 4;

#define LD_WF(mat, k0, n0) \
    (*(const s8v*)(fragLDS + ((((mat)*2 + (k0))*4 + (n0)) * 512) + lane * 8))

    float be1_c[4], w128_c[4], w129_c[4], w130_c[4], be2_c[4], bc1_c[4], wc2_c[4];
    #pragma unroll
    for (int n0 = 0; n0 < 4; ++n0) {
        const int n = n0 * 16 + l15;
        be1_c[n0]  = be1[n];
        w128_c[n0] = We1[128 * 64 + n];
        w129_c[n0] = We1[129 * 64 + n];
        w130_c[n0] = We1[130 * 64 + n];
        be2_c[n0]  = be2[n];
        bc1_c[n0]  = bc1[n];
        wc2_c[n0]  = Wc2[n];
    }

    ushort_t* yw = ldsY[wid];
    const ushort_t* yrow = yw + l15 * 72;

    for (int n = blockIdx.x * 8 + wid; n < N; n += totalWaves) {
        const int deg = cnt_i[n];
        const int effdeg = deg < SLOTMAX ? deg : SLOTMAX;
        const float cnx = coord[n * 3 + 0];
        const float cny = coord[n * 3 + 1];
        const float cnz = coord[n * 3 + 2];

        // ---- row-half of layer1, once per node (A rows all = h[n]) ----
        const ushort_t* hn = hbf + (size_t)n * 64;
        const s8v aN0 = *(const s8v*)(hn + g * 8);
        const s8v aN1 = *(const s8v*)(hn + 32 + g * 8);
        f32x4 rowacc[4];
        #pragma unroll
        for (int n0 = 0; n0 < 4; ++n0) {
            f32x4 a = {0.f, 0.f, 0.f, 0.f};
            a = __builtin_amdgcn_mfma_f32_16x16x32_bf16(aN0, LD_WF(0, 0, n0), a, 0, 0, 0);
            a = __builtin_amdgcn_mfma_f32_16x16x32_bf16(aN1, LD_WF(0, 1, n0), a, 0, 0, 0);
            rowacc[n0] = a;
        }

        float hsum[4] = {0.f, 0.f, 0.f, 0.f};
        float txs = 0.f, tys = 0.f, tzs = 0.f;
        const int ntile = (effdeg + 15) >> 4;

        for (int t = 0; t < ntile; ++t) {
            const int s = t * 16 + l15;
            const bool val = (s < effdeg);
            const int eL = slots[(size_t)n * SLOTMAX + (val ? s : 0)];
            const int ci = ei[E + eL];
            const float cx = coord[ci * 3 + 0];
            const float cy = coord[ci * 3 + 1];
            const float cz = coord[ci * 3 + 2];
            const float dx = cnx - cx, dy = cny - cy, dz = cnz - cz;
            const float radial = dx * dx + dy * dy + dz * dz;
            const float2 a2 = *(const float2*)(ea + (size_t)eL * 2);
            const ushort_t* hc = hbf + (size_t)ci * 64;
            const s8v aC0 = *(const s8v*)(hc + g * 8);
            const s8v aC1 = *(const s8v*)(hc + 32 + g * 8);

            // ---- layer1 col-half on top of rowacc ----
            f32x4 acc[4];
            #pragma unroll
            for (int n0 = 0; n0 < 4; ++n0) {
                f32x4 a = rowacc[n0];
                a = __builtin_amdgcn_mfma_f32_16x16x32_bf16(aC0, LD_WF(1, 0, n0), a, 0, 0, 0);
                a = __builtin_amdgcn_mfma_f32_16x16x32_bf16(aC1, LD_WF(1, 1, n0), a, 0, 0, 0);
                acc[n0] = a;
            }

            // ---- layer1 epilogue: rank-3 via shuffles, silu -> ldsY ----
            #pragma unroll
            for (int jj = 0; jj < 4; ++jj) {
                const int m = g * 4 + jj;
                const float rad_m = __shfl(radial, m, 16);
                const float a0_m  = __shfl(a2.x,  m, 16);
                const float a1_m  = __shfl(a2.y,  m, 16);
                #pragma unroll
                for (int n0 = 0; n0 < 4; ++n0) {
                    float y = acc[n0][jj] + be1_c[n0] + rad_m * w128_c[n0]
                            + a0_m * w129_c[n0] + a1_m * w130_c[n0];
                    yw[m * 72 + n0 * 16 + l15] = f2bf(silu_f(y));
                }
            }
            WAVE_FENCE();

            // ---- layer2 + register aggregation of edge_feat ----
            {
                const s8v b0 = *(const s8v*)(yrow + g * 8);
                const s8v b1 = *(const s8v*)(yrow + 32 + g * 8);
                #pragma unroll
                for (int n0 = 0; n0 < 4; ++n0) {
                    f32x4 a = {0.f, 0.f, 0.f, 0.f};
                    a = __builtin_amdgcn_mfma_f32_16x16x32_bf16(b0, LD_WF(2, 0, n0), a, 0, 0, 0);
                    a = __builtin_amdgcn_mfma_f32_16x16x32_bf16(b1, LD_WF(2, 1, n0), a, 0, 0, 0);
                    #pragma unroll
                    for (int jj = 0; jj < 4; ++jj) {
                        const float y2 = silu_f(a[jj] + be2_c[n0]);
                        const bool vj = (t * 16 + g * 4 + jj) < effdeg;
                        hsum[n0] += vj ? y2 : 0.0f;
                        yw[(g * 4 + jj) * 72 + n0 * 16 + l15] = f2bf(y2);
                    }
                }
            }
            WAVE_FENCE();

            // ---- coord head 64->64->1 + register trans accumulation ----
            {
                const s8v c0 = *(const s8v*)(yrow + g * 8);
                const s8v c1 = *(const s8v*)(yrow + 32 + g * 8);
                float p[4] = {0.f, 0.f, 0.f, 0.f};
                #pragma unroll
                for (int n0 = 0; n0 < 4; ++n0) {
                    f32x4 a = {0.f, 0.f, 0.f, 0.f};
                    a = __builtin_amdgcn_mfma_f32_16x16x32_bf16(c0, LD_WF(3, 0, n0), a, 0, 0, 0);
                    a = __builtin_amdgcn_mfma_f32_16x16x32_bf16(c1, LD_WF(3, 1, n0), a, 0, 0, 0);
                    #pragma unroll
                    for (int jj = 0; jj < 4; ++jj)
                        p[jj] += silu_f(a[jj] + bc1_c[n0]) * wc2_c[n0];
                }
                #pragma unroll
                for (int jj = 0; jj < 4; ++jj) {
                    p[jj] += __shfl_xor(p[jj], 1, 64);
                    p[jj] += __shfl_xor(p[jj], 2, 64);
                    p[jj] += __shfl_xor(p[jj], 4, 64);
                    p[jj] += __shfl_xor(p[jj], 8, 64);
                }
                // lane with l15 == 4g+jj owns edge m (has dx AND p[jj])
                #pragma unroll
                for (int jj = 0; jj < 4; ++jj) {
                    const int m = g * 4 + jj;
                    if (l15 == m && (t * 16 + m) < effdeg) {
                        const float sc = p[jj];
                        txs += clamp100(dx * sc);
                        tys += clamp100(dy * sc);
                        tzs += clamp100(dz * sc);
                    }
                }
            }
        }

        // ---- node epilogue: reduce + plain stores ----
        #pragma unroll
        for (int n0 = 0; n0 < 4; ++n0) {
            hsum[n0] += __shfl_xor(hsum[n0], 16, 64);
            hsum[n0] += __shfl_xor(hsum[n0], 32, 64);
        }
        if (g == 0) {
            #pragma unroll
            for (int n0 = 0; n0 < 4; ++n0)
                aggbf[(size_t)n * 64 + n0 * 16 + l15] = f2bf(hsum[n0]);
        }
        #pragma unroll
        for (int msk = 1; msk < 64; msk <<= 1) {
            txs += __shfl_xor(txs, msk, 64);
            tys += __shfl_xor(tys, msk, 64);
            tzs += __shfl_xor(tzs, msk, 64);
        }
        if (lane == 0) {
            const float inv = 1.0f / fmaxf((float)deg, 1.0f);
            coord_out[(size_t)n * 3 + 0] = cnx + txs * inv;
            coord_out[(size_t)n * 3 + 1] = cny + tys * inv;
            coord_out[(size_t)n * 3 + 2] = cnz + tzs * inv;
        }
    }
#undef LD_WF
}

// ---------------------------------------------------------------------------
// Node kernel: one wave per 16 nodes, MFMA over [h||agg] (K=128) -> 64 -> 64.
// ---------------------------------------------------------------------------
__global__ __launch_bounds__(NTE, 4) void egcl_node(
    const ushort_t* __restrict__ hbf,
    const ushort_t* __restrict__ aggbf,
    const ushort_t* __restrict__ wfG,   // base of wf; node mats at +16384
    const float* __restrict__ h,
    const float* __restrict__ bn1,
    const float* __restrict__ bn2,
    float* __restrict__ h_out,
    int N)
{
    __shared__ ushort_t fragLDS[12288];      // mats 4..6, 24 KB
    __shared__ ushort_t ldsY[8][16 * 72];

    const int tid = threadIdx.x;
    #pragma unroll
    for (int i = 0; i < 3; ++i)
        ((uint4*)fragLDS)[tid + i * 512] = ((const uint4*)(wfG + 16384))[tid + i * 512];
    __syncthreads();

    const int wid  = tid >> 6;
    const int lane = tid & 63;
    const int l15  = lane & 15;
    const int g    = lane >> 4;

#define LD_WN(mat, k0, n0) \
    (*(const s8v*)(fragLDS + ((((mat)*2 + (k0))*4 + (n0)) * 512) + lane * 8))

    float bn1_c[4], bn2_c[4];
    #pragma unroll
    for (int n0 = 0; n0 < 4; ++n0) {
        bn1_c[n0] = bn1[n0 * 16 + l15];
        bn2_c[n0] = bn2[n0 * 16 + l15];
    }

    const int wg = blockIdx.x * 8 + wid;
    const int nb = wg * 16;
    if (nb >= N) return;

    const int nod  = nb + l15;
    const int nodL = nod < N ? nod : N - 1;
    const ushort_t* hrow = hbf   + (size_t)nodL * 64;
    const ushort_t* arow = aggbf + (size_t)nodL * 64;
    const s8v aH0 = *(const s8v*)(hrow + g * 8);
    const s8v aH1 = *(const s8v*)(hrow + 32 + g * 8);
    const s8v aG0 = *(const s8v*)(arow + g * 8);
    const s8v aG1 = *(const s8v*)(arow + 32 + g * 8);

    ushort_t* yw = ldsY[wid];
    #pragma unroll
    for (int n0 = 0; n0 < 4; ++n0) {
        f32x4 a = {0.f, 0.f, 0.f, 0.f};
        a = __builtin_amdgcn_mfma_f32_16x16x32_bf16(aH0, LD_WN(0, 0, n0), a, 0, 0, 0);
        a = __builtin_amdgcn_mfma_f32_16x16x32_bf16(aH1, LD_WN(0, 1, n0), a, 0, 0, 0);
        a = __builtin_amdgcn_mfma_f32_16x16x32_bf16(aG0, LD_WN(1, 0, n0), a, 0, 0, 0);
        a = __builtin_amdgcn_mfma_f32_16x16x32_bf16(aG1, LD_WN(1, 1, n0), a, 0, 0, 0);
        #pragma unroll
        for (int jj = 0; jj < 4; ++jj)
            yw[(g * 4 + jj) * 72 + n0 * 16 + l15] = f2bf(silu_f(a[jj] + bn1_c[n0]));
    }
    WAVE_FENCE();

    const ushort_t* yrow = yw + l15 * 72;
    const s8v b0 = *(const s8v*)(yrow + g * 8);
    const s8v b1 = *(const s8v*)(yrow + 32 + g * 8);
    #pragma unroll
    for (int n0 = 0; n0 < 4; ++n0) {
        f32x4 a = {0.f, 0.f, 0.f, 0.f};
        a = __builtin_amdgcn_mfma_f32_16x16x32_bf16(b0, LD_WN(2, 0, n0), a, 0, 0, 0);
        a = __builtin_amdgcn_mfma_f32_16x16x32_bf16(b1, LD_WN(2, 1, n0), a, 0, 0, 0);
        #pragma unroll
        for (int jj = 0; jj < 4; ++jj) {
            const int m = nb + g * 4 + jj;
            if (m < N) {
                const size_t idx = (size_t)m * 64 + n0 * 16 + l15;
                h_out[idx] = h[idx] + (a[jj] + bn2_c[n0]);
            }
        }
    }
#undef LD_WN
}

extern "C" void kernel_launch(void* const* d_in, const int* in_sizes, int n_in,
                              void* d_out, int out_size, void* d_ws, size_t ws_size,
                              hipStream_t stream) {
    const float* h     = (const float*)d_in[0];
    const float* coord = (const float*)d_in[1];
    const int*   ei    = (const int*)  d_in[2];
    const float* ea    = (const float*)d_in[3];
    const float* We1   = (const float*)d_in[4];
    const float* be1   = (const float*)d_in[5];
    const float* We2   = (const float*)d_in[6];
    const float* be2   = (const float*)d_in[7];
    const float* Wn1   = (const float*)d_in[8];
    const float* bn1   = (const float*)d_in[9];
    const float* Wn2   = (const float*)d_in[10];
    const float* bn2   = (const float*)d_in[11];
    const float* Wc1   = (const float*)d_in[12];
    const float* bc1   = (const float*)d_in[13];
    const float* Wc2   = (const float*)d_in[14];

    const int N = in_sizes[0] / DD;     // h is [N,64]
    const int E = in_sizes[3] / 2;      // edge_attr is [E,2]

    float* out       = (float*)d_out;
    float* h_out     = out;
    float* coord_out = out + (size_t)N * DD;

    // workspace layout (all offsets 16B-aligned)
    char* base = (char*)d_ws;
    ushort_t* hbf   = (ushort_t*)base;                              // N*64*2 B
    const size_t o_wf    = (size_t)N * DD * 2;
    ushort_t* wf    = (ushort_t*)(base + o_wf);                     // 7*4096*2 B
    const size_t o_agg   = o_wf + 7 * 4096 * 2;
    ushort_t* aggbf = (ushort_t*)(base + o_agg);                    // N*64*2 B
    const size_t o_cnt   = o_agg + (size_t)N * DD * 2;
    int* cnt_i      = (int*)(base + o_cnt);                         // N*4 B
    const size_t o_slots = o_cnt + (size_t)N * 4;
    int* slots      = (int*)(base + o_slots);                       // N*SLOTMAX*4 B

    hipMemsetAsync((void*)cnt_i, 0, (size_t)N * 4, stream);

    // combined prep: hist+slots | h->bf16 | weight frags
    const int histBlocks = (E + 255) / 256;
    const int total8     = N * DD / 8;
    const int hbfBlocks  = (total8 + 255) / 256;
    const int wfBlocks   = (7 * 4096 + 255) / 256;
    prep_all<<<histBlocks + hbfBlocks + wfBlocks, 256, 0, stream>>>(
        h, We1, We2, Wc1, Wn1, Wn2, ei, hbf, wf, cnt_i, slots,
        E, total8, histBlocks, hbfBlocks);

    // edge: persistent, one wave per node
    const int eblocks = 768;
    const int totalWaves = eblocks * 8;
    egcl_edge<<<eblocks, NTE, 0, stream>>>(
        hbf, wf, coord, ei, ea, We1, be1, be2, bc1, Wc2,
        cnt_i, slots, aggbf, coord_out, N, E, totalWaves);

    // node: one wave per 16 nodes
    const int nwaves  = (N + 15) / 16;
    const int nblocks = (nwaves + 7) / 8;
    egcl_node<<<nblocks, NTE, 0, stream>>>(
        hbf, aggbf, wf, h, bn1, bn2, h_out, N);
}

// Round 5
// 250.396 us; speedup vs baseline: 12.0543x; 1.0196x over previous
//
#include <hip/hip_runtime.h>

#define DD 64
#define NTE 512
#define SLOTMAX 64

using s8v   = __attribute__((ext_vector_type(8))) short;   // 8 bf16 (4 VGPRs)
using f32x4 = __attribute__((ext_vector_type(4))) float;   // MFMA C/D

typedef unsigned int   uint_t;
typedef unsigned short ushort_t;

union U8 { s8v v; uint_t u[4]; };

__device__ __forceinline__ float silu_f(float x) {
    return x / (1.0f + __expf(-x));
}
__device__ __forceinline__ float clamp100(float x) {
    return fminf(fmaxf(x, -100.0f), 100.0f);
}
__device__ __forceinline__ unsigned short f2bf(float x) {
    unsigned int u = __float_as_uint(x);
    return (unsigned short)((u + 0x7FFFu + ((u >> 16) & 1u)) >> 16);   // RNE
}
__device__ __forceinline__ uint_t cvt_pk_bf16(float lo, float hi) {
    uint_t r;
    asm("v_cvt_pk_bf16_f32 %0, %1, %2" : "=v"(r) : "v"(lo), "v"(hi));
    return r;
}

#define WAVE_FENCE() do { asm volatile("s_waitcnt lgkmcnt(0)" ::: "memory"); \
                          __builtin_amdgcn_sched_barrier(0); } while (0)

// ---------------------------------------------------------------------------
// Combined prep kernel.
//  wf layout (shorts):
//   mats 0..6 (plain or remapped k), 4096 each:
//     idx = (((mat*2+k0)*4+n0)*64 + lane)*8 + i ; m = n0*16+(lane&15)
//     mats 0/1: We1 rows 0-63 / 64-127, plain k = k0*32+8*(lane>>4)+i
//     mats 2/3: We2 / Wc1 with REMAPPED k = 16*(2*k0+(i>>2)) + 4*(lane>>4) + (i&3)
//     mats 4/5/6: Wn1a / Wn1b / Wn2, plain k (node kernel, old convention)
//   mat7  @28672 (2048): rows [We1[128], We1[129], We1[130], be1], plain k (k<4)
//   mat8  @30720 (2048): rows [be2, bc1], plain k (k<2)
// ---------------------------------------------------------------------------
__global__ __launch_bounds__(256) void prep_all(
    const float* __restrict__ h,
    const float* __restrict__ We1, const float* __restrict__ We2,
    const float* __restrict__ Wc1,
    const float* __restrict__ Wn1, const float* __restrict__ Wn2,
    const float* __restrict__ be1, const float* __restrict__ be2,
    const float* __restrict__ bc1,
    const int*   __restrict__ ei,
    ushort_t* __restrict__ hbf,
    ushort_t* __restrict__ wf,
    int* __restrict__ cnt_i,
    int* __restrict__ slots,
    int E, int total8, int histBlocks, int hbfBlocks)
{
    const int b = blockIdx.x;
    if (b < histBlocks) {
        const int e = b * 256 + threadIdx.x;
        if (e < E) {
            const int r = ei[e];
            const int s = atomicAdd(&cnt_i[r], 1);
            if (s < SLOTMAX) slots[(size_t)r * SLOTMAX + s] = e;
        }
    } else if (b < histBlocks + hbfBlocks) {
        const int t = (b - histBlocks) * 256 + threadIdx.x;
        if (t < total8) {
            const float4 v0 = ((const float4*)h)[t * 2 + 0];
            const float4 v1 = ((const float4*)h)[t * 2 + 1];
            uint4 o;
            o.x = (uint_t)f2bf(v0.x) | ((uint_t)f2bf(v0.y) << 16);
            o.y = (uint_t)f2bf(v0.z) | ((uint_t)f2bf(v0.w) << 16);
            o.z = (uint_t)f2bf(v1.x) | ((uint_t)f2bf(v1.y) << 16);
            o.w = (uint_t)f2bf(v1.z) | ((uint_t)f2bf(v1.w) << 16);
            ((uint4*)hbf)[t] = o;
        }
    } else {
        const int t = (b - histBlocks - hbfBlocks) * 256 + threadIdx.x;
        if (t >= 32768) return;
        if (t < 28672) {
            const int j    = t & 7;
            const int lane = (t >> 3) & 63;
            const int n0   = (t >> 9) & 3;
            const int k0   = (t >> 11) & 1;
            const int mat  = t >> 12;
            const int g    = lane >> 4;
            int k;
            if (mat == 2 || mat == 3) k = 16 * (2 * k0 + (j >> 2)) + 4 * g + (j & 3);
            else                      k = k0 * 32 + g * 8 + j;
            const int n = n0 * 16 + (lane & 15);
            float v;
            if      (mat == 0) v = We1[(size_t)k * 64 + n];
            else if (mat == 1) v = We1[(size_t)(64 + k) * 64 + n];
            else if (mat == 2) v = We2[(size_t)k * 64 + n];
            else if (mat == 3) v = Wc1[(size_t)k * 64 + n];
            else if (mat == 4) v = Wn1[(size_t)k * 64 + n];
            else if (mat == 5) v = Wn1[(size_t)(64 + k) * 64 + n];
            else               v = Wn2[(size_t)k * 64 + n];
            wf[t] = f2bf(v);
        } else {
            const int t2   = t - 28672;
            const int j    = t2 & 7;
            const int lane = (t2 >> 3) & 63;
            const int n0   = (t2 >> 9) & 3;
            const int xm   = (t2 >> 11) & 1;
            const int k = 8 * (lane >> 4) + j;
            const int m = n0 * 16 + (lane & 15);
            float v = 0.0f;
            if (xm == 0) {
                if      (k == 0) v = We1[(size_t)128 * 64 + m];
                else if (k == 1) v = We1[(size_t)129 * 64 + m];
                else if (k == 2) v = We1[(size_t)130 * 64 + m];
                else if (k == 3) v = be1[m];
            } else {
                if      (k == 0) v = be2[m];
                else if (k == 1) v = bc1[m];
            }
            wf[t] = f2bf(v);
        }
    }
}

// ---------------------------------------------------------------------------
// Edge kernel: one WAVE per NODE, weights-as-A / activations-as-B MFMA.
// D layout: row = out-dim (4g+j+16*m0), col = edge (l15). The k-remapped
// We2/Wc1 prepack makes each layer's output fragment directly the next
// layer's B fragment for the SAME lane -> in-register chain, no LDS, no
// fences, 8 cvt_pk per transition. Rank-3 + biases folded into MFMA rows.
// ---------------------------------------------------------------------------
__global__ __launch_bounds__(NTE, 4) void egcl_edge(
    const ushort_t* __restrict__ hbf,
    const ushort_t* __restrict__ wfG,
    const float* __restrict__ coord,
    const int*   __restrict__ ei,
    const float* __restrict__ ea,
    const float* __restrict__ Wc2,
    const int* __restrict__ cnt_i,
    const int* __restrict__ slots,
    ushort_t* __restrict__ aggbf,    // [N,64] bf16 (sum of edge_feat)
    float* __restrict__ coord_out,   // [N,3]
    int N, int E, int totalWaves)
{
    __shared__ ushort_t fragLDS[20480];   // mats 0..3 + mat7 + mat8 = 40 KB

    const int tid = threadIdx.x;
    #pragma unroll
    for (int i = 0; i < 4; ++i)
        ((uint4*)fragLDS)[tid + i * 512] = ((const uint4*)wfG)[tid + i * 512];
    ((uint4*)fragLDS)[2048 + tid] = ((const uint4*)wfG)[3584 + tid];
    __syncthreads();

    const int wid  = tid >> 6;
    const int lane = tid & 63;
    const int l15  = lane & 15;
    const int g    = lane >> 4;

#define LD_W(mat, k0, m0) \
    (*(const s8v*)(fragLDS + ((((mat)*2 + (k0))*4 + (m0)) * 512) + lane * 8))
#define LD_X7(m0) (*(const s8v*)(fragLDS + 16384 + (m0) * 512 + lane * 8))
#define LD_XB(m0) (*(const s8v*)(fragLDS + 18432 + (m0) * 512 + lane * 8))

    // hoisted constants
    float wc2_c[4][4];
    #pragma unroll
    for (int m0 = 0; m0 < 4; ++m0)
        #pragma unroll
        for (int j = 0; j < 4; ++j)
            wc2_c[m0][j] = Wc2[m0 * 16 + 4 * g + j];

    U8 b2f, bcf;   // constant bias-selector B fragments (rows >=2 of mat8 are 0)
    b2f.u[0] = 0x00003F80u; b2f.u[1] = 0; b2f.u[2] = 0; b2f.u[3] = 0;  // [1,0,..]
    bcf.u[0] = 0x3F800000u; bcf.u[1] = 0; bcf.u[2] = 0; bcf.u[3] = 0;  // [0,1,..]

    const f32x4 zero4 = {0.f, 0.f, 0.f, 0.f};

    int n = blockIdx.x * 8 + wid;
    int pdeg = 0, pslot = 0;
    if (n < N) {
        pdeg  = cnt_i[n];
        pslot = slots[(size_t)n * SLOTMAX + l15];
    }

    for (; n < N; n += totalWaves) {
        const int deg   = pdeg;
        const int slot0 = pslot;
        const int nn = n + totalWaves;
        if (nn < N) {                       // prefetch next node (independent)
            pdeg  = cnt_i[nn];
            pslot = slots[(size_t)nn * SLOTMAX + l15];
        }

        const int effdeg = deg < SLOTMAX ? deg : SLOTMAX;
        const float cnx = coord[n * 3 + 0];
        const float cny = coord[n * 3 + 1];
        const float cnz = coord[n * 3 + 2];
        const int slot0_l0 = __shfl(slot0, lane & 48, 64);

        // row-half of layer1 once per node: rowacc = W1a^T x h[n] (broadcast B)
        const ushort_t* hn = hbf + (size_t)n * 64;
        const s8v bn0 = *(const s8v*)(hn + g * 8);
        const s8v bn1 = *(const s8v*)(hn + 32 + g * 8);
        f32x4 rowacc[4];
        #pragma unroll
        for (int m0 = 0; m0 < 4; ++m0) {
            f32x4 a = zero4;
            a = __builtin_amdgcn_mfma_f32_16x16x32_bf16(LD_W(0, 0, m0), bn0, a, 0, 0, 0);
            a = __builtin_amdgcn_mfma_f32_16x16x32_bf16(LD_W(0, 1, m0), bn1, a, 0, 0, 0);
            rowacc[m0] = a;
        }

        float hsum[4][4];
        #pragma unroll
        for (int m0 = 0; m0 < 4; ++m0)
            #pragma unroll
            for (int j = 0; j < 4; ++j) hsum[m0][j] = 0.f;
        float txs = 0.f, tys = 0.f, tzs = 0.f;

        const int ntile = (effdeg + 15) >> 4;
        for (int t = 0; t < ntile; ++t) {
            const int s = t * 16 + l15;
            const bool val = (s < effdeg);
            int eL;
            if (t == 0) eL = val ? slot0 : slot0_l0;
            else        eL = slots[(size_t)n * SLOTMAX + (val ? s : 0)];

            const int ci = ei[E + eL];
            const float cx = coord[ci * 3 + 0];
            const float cy = coord[ci * 3 + 1];
            const float cz = coord[ci * 3 + 2];
            const float dx = cnx - cx, dy = cny - cy, dz = cnz - cz;
            const float radial = dx * dx + dy * dy + dz * dz;
            const float2 a2 = *(const float2*)(ea + (size_t)eL * 2);
            const ushort_t* hc = hbf + (size_t)ci * 64;
            const s8v bc0 = *(const s8v*)(hc + g * 8);
            const s8v bc1v = *(const s8v*)(hc + 32 + g * 8);

            U8 ex;   // extra k-block input: [radial, ea0, ea1, 1] (rows>=4 of mat7 = 0)
            ex.u[0] = cvt_pk_bf16(radial, a2.x);
            ex.u[1] = cvt_pk_bf16(a2.y, 1.0f);
            ex.u[2] = 0; ex.u[3] = 0;

            // ---- layer 1 ----
            f32x4 c1[4];
            #pragma unroll
            for (int m0 = 0; m0 < 4; ++m0) {
                f32x4 a = rowacc[m0];
                a = __builtin_amdgcn_mfma_f32_16x16x32_bf16(LD_W(1, 0, m0), bc0,  a, 0, 0, 0);
                a = __builtin_amdgcn_mfma_f32_16x16x32_bf16(LD_W(1, 1, m0), bc1v, a, 0, 0, 0);
                a = __builtin_amdgcn_mfma_f32_16x16x32_bf16(LD_X7(m0),      ex.v, a, 0, 0, 0);
                c1[m0] = a;
            }

            // silu + in-register repack to next layer's B fragment
            U8 f2a, f2b;
            #pragma unroll
            for (int m0 = 0; m0 < 4; ++m0) {
                const float ya = silu_f(c1[m0][0]);
                const float yb = silu_f(c1[m0][1]);
                const float yc = silu_f(c1[m0][2]);
                const float yd = silu_f(c1[m0][3]);
                U8& dst = (m0 < 2) ? f2a : f2b;
                dst.u[(m0 & 1) * 2 + 0] = cvt_pk_bf16(ya, yb);
                dst.u[(m0 & 1) * 2 + 1] = cvt_pk_bf16(yc, yd);
            }

            // ---- layer 2 (edge_feat) ----
            f32x4 c2[4];
            #pragma unroll
            for (int m0 = 0; m0 < 4; ++m0) {
                f32x4 a = zero4;
                a = __builtin_amdgcn_mfma_f32_16x16x32_bf16(LD_W(2, 0, m0), f2a.v, a, 0, 0, 0);
                a = __builtin_amdgcn_mfma_f32_16x16x32_bf16(LD_W(2, 1, m0), f2b.v, a, 0, 0, 0);
                a = __builtin_amdgcn_mfma_f32_16x16x32_bf16(LD_XB(m0),      b2f.v, a, 0, 0, 0);
                c2[m0] = a;
            }

            U8 f3a, f3b;
            #pragma unroll
            for (int m0 = 0; m0 < 4; ++m0) {
                const float ya = silu_f(c2[m0][0]);
                const float yb = silu_f(c2[m0][1]);
                const float yc = silu_f(c2[m0][2]);
                const float yd = silu_f(c2[m0][3]);
                hsum[m0][0] += val ? ya : 0.f;
                hsum[m0][1] += val ? yb : 0.f;
                hsum[m0][2] += val ? yc : 0.f;
                hsum[m0][3] += val ? yd : 0.f;
                U8& dst = (m0 < 2) ? f3a : f3b;
                dst.u[(m0 & 1) * 2 + 0] = cvt_pk_bf16(ya, yb);
                dst.u[(m0 & 1) * 2 + 1] = cvt_pk_bf16(yc, yd);
            }

            // ---- coord head: 64 -> 64 -> 1 ----
            float p = 0.f;
            #pragma unroll
            for (int m0 = 0; m0 < 4; ++m0) {
                f32x4 a = zero4;
                a = __builtin_amdgcn_mfma_f32_16x16x32_bf16(LD_W(3, 0, m0), f3a.v, a, 0, 0, 0);
                a = __builtin_amdgcn_mfma_f32_16x16x32_bf16(LD_W(3, 1, m0), f3b.v, a, 0, 0, 0);
                a = __builtin_amdgcn_mfma_f32_16x16x32_bf16(LD_XB(m0),      bcf.v, a, 0, 0, 0);
                #pragma unroll
                for (int j = 0; j < 4; ++j)
                    p = fmaf(silu_f(a[j]), wc2_c[m0][j], p);
            }
            p += __shfl_xor(p, 16, 64);
            p += __shfl_xor(p, 32, 64);
            const float sc = val ? p : 0.f;
            txs += clamp100(dx * sc);   // 4x redundant across g; /4 folded below
            tys += clamp100(dy * sc);
            tzs += clamp100(dz * sc);
        }

        // ---- node epilogue ----
        #pragma unroll
        for (int m0 = 0; m0 < 4; ++m0) {
            #pragma unroll
            for (int j = 0; j < 4; ++j) {
                float v = hsum[m0][j];
                v += __shfl_xor(v, 1, 64);
                v += __shfl_xor(v, 2, 64);
                v += __shfl_xor(v, 4, 64);
                v += __shfl_xor(v, 8, 64);
                hsum[m0][j] = v;
            }
        }
        if (l15 == 0) {
            uint_t* ab = (uint_t*)aggbf + (size_t)n * 32 + 2 * g;
            #pragma unroll
            for (int m0 = 0; m0 < 4; ++m0) {
                ab[8 * m0 + 0] = cvt_pk_bf16(hsum[m0][0], hsum[m0][1]);
                ab[8 * m0 + 1] = cvt_pk_bf16(hsum[m0][2], hsum[m0][3]);
            }
        }
        #pragma unroll
        for (int msk = 1; msk < 64; msk <<= 1) {
            txs += __shfl_xor(txs, msk, 64);
            tys += __shfl_xor(tys, msk, 64);
            tzs += __shfl_xor(tzs, msk, 64);
        }
        if (lane == 0) {
            const float inv = 0.25f / fmaxf((float)deg, 1.0f);
            coord_out[(size_t)n * 3 + 0] = cnx + txs * inv;
            coord_out[(size_t)n * 3 + 1] = cny + tys * inv;
            coord_out[(size_t)n * 3 + 2] = cnz + tzs * inv;
        }
    }
#undef LD_W
#undef LD_X7
#undef LD_XB
}

// ---------------------------------------------------------------------------
// Node kernel: one wave per 16 nodes, MFMA over [h||agg] (K=128) -> 64 -> 64.
// (old convention: activations as A, weights as B; mats 4..6 plain k)
// ---------------------------------------------------------------------------
__global__ __launch_bounds__(NTE, 4) void egcl_node(
    const ushort_t* __restrict__ hbf,
    const ushort_t* __restrict__ aggbf,
    const ushort_t* __restrict__ wfG,   // node mats at +16384
    const float* __restrict__ h,
    const float* __restrict__ bn1,
    const float* __restrict__ bn2,
    float* __restrict__ h_out,
    int N)
{
    __shared__ ushort_t fragLDS[12288];      // mats 4..6, 24 KB
    __shared__ ushort_t ldsY[8][16 * 72];

    const int tid = threadIdx.x;
    #pragma unroll
    for (int i = 0; i < 3; ++i)
        ((uint4*)fragLDS)[tid + i * 512] = ((const uint4*)(wfG + 16384))[tid + i * 512];
    __syncthreads();

    const int wid  = tid >> 6;
    const int lane = tid & 63;
    const int l15  = lane & 15;
    const int g    = lane >> 4;

#define LD_WN(mat, k0, n0) \
    (*(const s8v*)(fragLDS + ((((mat)*2 + (k0))*4 + (n0)) * 512) + lane * 8))

    float bn1_c[4], bn2_c[4];
    #pragma unroll
    for (int n0 = 0; n0 < 4; ++n0) {
        bn1_c[n0] = bn1[n0 * 16 + l15];
        bn2_c[n0] = bn2[n0 * 16 + l15];
    }

    const int wg = blockIdx.x * 8 + wid;
    const int nb = wg * 16;
    if (nb >= N) return;

    const int nod  = nb + l15;
    const int nodL = nod < N ? nod : N - 1;
    const ushort_t* hrow = hbf   + (size_t)nodL * 64;
    const ushort_t* arow = aggbf + (size_t)nodL * 64;
    const s8v aH0 = *(const s8v*)(hrow + g * 8);
    const s8v aH1 = *(const s8v*)(hrow + 32 + g * 8);
    const s8v aG0 = *(const s8v*)(arow + g * 8);
    const s8v aG1 = *(const s8v*)(arow + 32 + g * 8);

    ushort_t* yw = ldsY[wid];
    #pragma unroll
    for (int n0 = 0; n0 < 4; ++n0) {
        f32x4 a = {0.f, 0.f, 0.f, 0.f};
        a = __builtin_amdgcn_mfma_f32_16x16x32_bf16(aH0, LD_WN(0, 0, n0), a, 0, 0, 0);
        a = __builtin_amdgcn_mfma_f32_16x16x32_bf16(aH1, LD_WN(0, 1, n0), a, 0, 0, 0);
        a = __builtin_amdgcn_mfma_f32_16x16x32_bf16(aG0, LD_WN(1, 0, n0), a, 0, 0, 0);
        a = __builtin_amdgcn_mfma_f32_16x16x32_bf16(aG1, LD_WN(1, 1, n0), a, 0, 0, 0);
        #pragma unroll
        for (int jj = 0; jj < 4; ++jj)
            yw[(g * 4 + jj) * 72 + n0 * 16 + l15] = f2bf(silu_f(a[jj] + bn1_c[n0]));
    }
    WAVE_FENCE();

    const ushort_t* yrow = yw + l15 * 72;
    const s8v b0 = *(const s8v*)(yrow + g * 8);
    const s8v b1 = *(const s8v*)(yrow + 32 + g * 8);
    #pragma unroll
    for (int n0 = 0; n0 < 4; ++n0) {
        f32x4 a = {0.f, 0.f, 0.f, 0.f};
        a = __builtin_amdgcn_mfma_f32_16x16x32_bf16(b0, LD_WN(2, 0, n0), a, 0, 0, 0);
        a = __builtin_amdgcn_mfma_f32_16x16x32_bf16(b1, LD_WN(2, 1, n0), a, 0, 0, 0);
        #pragma unroll
        for (int jj = 0; jj < 4; ++jj) {
            const int m = nb + g * 4 + jj;
            if (m < N) {
                const size_t idx = (size_t)m * 64 + n0 * 16 + l15;
                h_out[idx] = h[idx] + (a[jj] + bn2_c[n0]);
            }
        }
    }
#undef LD_WN
}

extern "C" void kernel_launch(void* const* d_in, const int* in_sizes, int n_in,
                              void* d_out, int out_size, void* d_ws, size_t ws_size,
                              hipStream_t stream) {
    const float* h     = (const float*)d_in[0];
    const float* coord = (const float*)d_in[1];
    const int*   ei    = (const int*)  d_in[2];
    const float* ea    = (const float*)d_in[3];
    const float* We1   = (const float*)d_in[4];
    const float* be1   = (const float*)d_in[5];
    const float* We2   = (const float*)d_in[6];
    const float* be2   = (const float*)d_in[7];
    const float* Wn1   = (const float*)d_in[8];
    const float* bn1   = (const float*)d_in[9];
    const float* Wn2   = (const float*)d_in[10];
    const float* bn2   = (const float*)d_in[11];
    const float* Wc1   = (const float*)d_in[12];
    const float* bc1   = (const float*)d_in[13];
    const float* Wc2   = (const float*)d_in[14];

    const int N = in_sizes[0] / DD;     // h is [N,64]
    const int E = in_sizes[3] / 2;      // edge_attr is [E,2]

    float* out       = (float*)d_out;
    float* h_out     = out;
    float* coord_out = out + (size_t)N * DD;

    // workspace layout (16B aligned)
    char* base = (char*)d_ws;
    ushort_t* hbf   = (ushort_t*)base;                              // N*64*2 B
    const size_t o_wf    = (size_t)N * DD * 2;
    ushort_t* wf    = (ushort_t*)(base + o_wf);                     // 32768*2 B
    const size_t o_agg   = o_wf + 32768 * 2;
    ushort_t* aggbf = (ushort_t*)(base + o_agg);                    // N*64*2 B
    const size_t o_cnt   = o_agg + (size_t)N * DD * 2;
    int* cnt_i      = (int*)(base + o_cnt);                         // N*4 B
    const size_t o_slots = o_cnt + (size_t)N * 4;
    int* slots      = (int*)(base + o_slots);                       // N*SLOTMAX*4 B

    hipMemsetAsync((void*)cnt_i, 0, (size_t)N * 4, stream);

    // combined prep: hist+slots | h->bf16 | weight frags
    const int histBlocks = (E + 255) / 256;
    const int total8     = N * DD / 8;
    const int hbfBlocks  = (total8 + 255) / 256;
    const int wfBlocks   = (32768 + 255) / 256;
    prep_all<<<histBlocks + hbfBlocks + wfBlocks, 256, 0, stream>>>(
        h, We1, We2, Wc1, Wn1, Wn2, be1, be2, bc1, ei,
        hbf, wf, cnt_i, slots, E, total8, histBlocks, hbfBlocks);

    // edge: persistent, one wave per node (512 blocks = fully resident at 2/CU)
    const int eblocks = 512;
    const int totalWaves = eblocks * 8;
    egcl_edge<<<eblocks, NTE, 0, stream>>>(
        hbf, wf, coord, ei, ea, Wc2,
        cnt_i, slots, aggbf, coord_out, N, E, totalWaves);

    // node: one wave per 16 nodes
    const int nwaves  = (N + 15) / 16;
    const int nblocks = (nwaves + 7) / 8;
    egcl_node<<<nblocks, NTE, 0, stream>>>(
        hbf, aggbf, wf, h, bn1, bn2, h_out, N);
}